// Round 5
// baseline (275.072 us; speedup 1.0000x reference)
//
#include <hip/hip_runtime.h>
#include <math.h>

// HOG (skimage-faithful): orientations=8, cell=16x16, 1x1 blocks, L2-Hys.
// Input: fake [B,3,512,512] f32 (NCHW). Output: [B, 32*32*8] f32.
//
// Round 5: back to R1's many-small-waves structure (65536 waves, ~80%
// VALUBusy measured in R1) + R2's verified thermometer binning (absmax 0.0).
// Fat-wave designs (R2-R4) never exceeded ~23% issue efficiency. Here each
// wave = 4 rows x 64 cols, 1 px/lane/row; all 42 neighbor values loaded as
// independent coalesced scalar loads up front (left/right reuse the same
// wave-uniform row base with +-1 col offset -> no shuffles, no lgkmcnt
// chains in the hot path). ~60 VALU/px vs R1's 450.
//
// Block = 256 = 4 waves stacked vertically = 16 rows x 64 cols = 4 cells.
// Grid = B * 32 cellrows * 8 colgroups = 16384 blocks.

namespace {

constexpr int Hh = 512;
constexpr int Ww = 512;
constexpr int CHN = 3;
constexpr int HW = Hh * Ww;
constexpr float TAN22 = 0.41421356237309503f;  // tan(22.5 deg)

__global__ __launch_bounds__(256, 6) void hog_kernel(const float* __restrict__ x,
                                                     float* __restrict__ out) {
    const int b    = blockIdx.x >> 8;
    const int cr   = (blockIdx.x >> 3) & 31;   // cell row
    const int cg   = blockIdx.x & 7;           // 64-col group
    const int tx   = threadIdx.x;
    const int lane = tx & 63;
    const int wid  = tx >> 6;                  // 0..3: 4-row strip
    const int r0   = cr * 16 + wid * 4;
    const int w    = cg * 64 + lane;

    const float* xb = x + (size_t)b * (CHN * HW);

    const int wl = (w == 0) ? 0 : w - 1;          // clamped: value unused when
    const int wr = (w == Ww - 1) ? Ww - 1 : w + 1;  // colEdge forces gcol = 0
    const bool colEdge = (w == 0) | (w == Ww - 1);

    // ---- all 42 values as independent coalesced scalar loads ----
    float V[CHN][6];                // center col, rows r0-1 .. r0+4 (clamped)
    float Lv[CHN][4], Rv[CHN][4];   // left/right cols, rows r0 .. r0+3
#pragma unroll
    for (int ch = 0; ch < CHN; ++ch) {
#pragma unroll
        for (int r = 0; r < 6; ++r) {
            int h = r0 - 1 + r;
            h = h < 0 ? 0 : (h > Hh - 1 ? Hh - 1 : h);  // clamped rows feed
            V[ch][r] = xb[(size_t)ch * HW + (size_t)h * Ww + w];  // rowEdge-zeroed
        }                                                          // gradients
#pragma unroll
        for (int r = 0; r < 4; ++r) {
            const float* rowp = xb + (size_t)ch * HW + (size_t)(r0 + r) * Ww;
            Lv[ch][r] = rowp[wl];   // same base as center row, +-1 col
            Rv[ch][r] = rowp[wr];
        }
    }

    float c[8];                     // cumulative thermometer histogram
#pragma unroll
    for (int o = 0; o < 8; ++o) c[o] = 0.f;

#pragma unroll
    for (int hh = 0; hh < 4; ++hh) {
        const int h = r0 + hh;
        const bool rowEdge = (h == 0) | (h == Hh - 1);   // wave-uniform

        float bm2 = -1.f, bgr = 0.f, bgc = 0.f;
#pragma unroll
        for (int ch = 0; ch < CHN; ++ch) {
            float gv = V[ch][hh + 2] - V[ch][hh];        // x[h+1]-x[h-1]
            gv = rowEdge ? 0.f : gv;
            float gc_ = Rv[ch][hh] - Lv[ch][hh];         // x[w+1]-x[w-1]
            gc_ = colEdge ? 0.f : gc_;
            const float m2 = fmaf(gv, gv, gc_ * gc_);
            if (m2 > bm2) { bm2 = m2; bgr = gv; bgc = gc_; }  // first-max
        }
        const float m = sqrtf(bm2);

        // flip into upper half-plane; (gr==0, gc<0) -> 180 deg -> bin 0
        const bool flip = (bgr < 0.f) | ((bgr == 0.f) & (bgc < 0.f));
        const float bb = flip ? -bgr : bgr;              // >= 0
        const float A  = flip ? -bgc : bgc;
        const float Aa = fabsf(A);
        const float p1 = Aa * TAN22;
        const float p2 = bb * TAN22;
        const bool q2  = (A <= 0.f);                     // ori >= 90
        const bool ge1 = (bb >= p1), ge2 = (bb >= Aa), ge3 = (p2 >= Aa);
        const bool gt1 = (bb > p1),  gt2 = (bb > Aa),  gt3 = (p2 > Aa);
        // c[k] == sum of m where ori >= 22.5k; hist by differencing later
        c[0] += m;
        c[1] += (q2 | ge1) ? m : 0.f;
        c[2] += (q2 | ge2) ? m : 0.f;
        c[3] += (q2 | ge3) ? m : 0.f;
        c[4] += q2 ? m : 0.f;
        c[5] += (q2 & !gt3) ? m : 0.f;
        c[6] += (q2 & !gt2) ? m : 0.f;
        c[7] += (q2 & !gt1) ? m : 0.f;
    }

    // 16 consecutive lanes = one 16-col cell (this wave's 4 rows of it)
#pragma unroll
    for (int o = 0; o < 8; ++o) {
        c[o] += __shfl_xor(c[o], 1, 64);
        c[o] += __shfl_xor(c[o], 2, 64);
        c[o] += __shfl_xor(c[o], 4, 64);
        c[o] += __shfl_xor(c[o], 8, 64);
    }

    __shared__ float lh[4][4][9];          // [strip][cell][bin], col 8 = 0
    if (tx < 16) lh[tx >> 2][tx & 3][8] = 0.f;
    if ((lane & 15) == 0) {
        const int cell = lane >> 4;
#pragma unroll
        for (int o = 0; o < 8; ++o) lh[wid][cell][o] = c[o];
    }
    __syncthreads();

    // 32 threads -> (cell 0..3, bin 0..7): finish hist + L2-Hys
    if (tx < 32) {
        const int cell = tx >> 3;
        const int o    = tx & 7;
        const float c_o  = lh[0][cell][o]     + lh[1][cell][o] +
                           lh[2][cell][o]     + lh[3][cell][o];
        const float c_o1 = lh[0][cell][o + 1] + lh[1][cell][o + 1] +
                           lh[2][cell][o + 1] + lh[3][cell][o + 1];
        const float hv = (c_o - c_o1) * (1.0f / 256.0f);   // cell mean

        float ss = hv * hv;                // L2-Hys over the 8-bin group
        ss += __shfl_xor(ss, 1, 64);
        ss += __shfl_xor(ss, 2, 64);
        ss += __shfl_xor(ss, 4, 64);
        float n1 = hv / sqrtf(ss + 1e-10f);   // eps^2 = (1e-5)^2
        n1 = fminf(n1, 0.2f);
        float s2 = n1 * n1;
        s2 += __shfl_xor(s2, 1, 64);
        s2 += __shfl_xor(s2, 2, 64);
        s2 += __shfl_xor(s2, 4, 64);
        const float nv = n1 / sqrtf(s2 + 1e-10f);

        out[(((size_t)b * 32 + cr) * 32 + (cg * 4 + cell)) * 8 + o] = nv;
    }
}

} // namespace

extern "C" void kernel_launch(void* const* d_in, const int* in_sizes, int n_in,
                              void* d_out, int out_size, void* d_ws, size_t ws_size,
                              hipStream_t stream) {
    (void)n_in; (void)out_size; (void)d_ws; (void)ws_size;
    const float* x = (const float*)d_in[0];
    float* out = (float*)d_out;
    const int B = in_sizes[0] / (CHN * HW);   // 64 for the bench shape
    const int grid = B * 32 * 8;              // batch * cellrows * colgroups
    hog_kernel<<<grid, 256, 0, stream>>>(x, out);
}